// Round 6
// baseline (621.055 us; speedup 1.0000x reference)
//
#include <hip/hip_runtime.h>
#include <hip/hip_bf16.h>
#include <math.h>

typedef __bf16 bf16;
typedef __bf16 bf16x8 __attribute__((ext_vector_type(8)));
typedef float f32x4 __attribute__((ext_vector_type(4)));

#define DIM 1280
#define SEQ 4096
#define NH 16
#define HD 80
#define HIDDEN 5120
#define FLAG_THRESH 4096

// counted-vmcnt + raw barrier (T4): s_barrier builtin does NOT drain vmcnt (unlike __syncthreads)
#define S_VMCNT(n) asm volatile("s_waitcnt vmcnt(" #n ")" ::: "memory")
#define S_BAR() __builtin_amdgcn_s_barrier()

__device__ __forceinline__ void gl_lds16(const bf16* g, bf16* l) {
  __builtin_amdgcn_global_load_lds((const __attribute__((address_space(1))) void*)g,
                                   (__attribute__((address_space(3))) void*)l, 16, 0, 0);
}

__device__ __forceinline__ f32x4 fz4() { f32x4 v; v.x = 0.f; v.y = 0.f; v.z = 0.f; v.w = 0.f; return v; }

__device__ __forceinline__ float ldx(const void* p, size_t i, bool f32) {
  if (f32) return ((const float*)p)[i];
  return (float)((const bf16*)p)[i];
}

// ---------------- flag prologue
__global__ void zero_flag_k(int* flag) { *flag = 0; }

__global__ __launch_bounds__(256) void sniff_k(const unsigned short* h, int n, int* flag) {
  int i = blockIdx.x * 256 + threadIdx.x;
  int c = 0;
  for (int idx = i; idx < n; idx += 256 * gridDim.x) {
    int e = (h[idx] >> 7) & 0xFF;
    c += (e >= 0xC8) ? 1 : 0;
  }
  #pragma unroll
  for (int o = 32; o; o >>= 1) c += __shfl_down(c, o);
  if ((threadIdx.x & 63) == 0 && c) atomicAdd(flag, c);
}

// ---------------- transpose+convert: in[R][C] -> out[C][R] bf16
__global__ __launch_bounds__(256) void transpose_k(const void* __restrict__ in, bf16* __restrict__ out,
                                                   int R, int C, const int* __restrict__ flag) {
  bool f32 = *flag > FLAG_THRESH;
  __shared__ bf16 tile[32][33];
  int c0 = blockIdx.x * 32, r0 = blockIdx.y * 32;
  int tx = threadIdx.x, ty = threadIdx.y;
  #pragma unroll
  for (int i = 0; i < 4; i++)
    tile[ty + 8 * i][tx] = (bf16)ldx(in, (size_t)(r0 + ty + 8 * i) * C + c0 + tx, f32);
  __syncthreads();
  #pragma unroll
  for (int i = 0; i < 4; i++)
    out[(size_t)(c0 + ty + 8 * i) * R + r0 + tx] = tile[tx][ty + 8 * i];
}

// ---------------- layernorm over 1280 cols, one block per row, out bf16
__global__ __launch_bounds__(256) void ln_k(const void* __restrict__ x, const void* __restrict__ sc,
                                            const void* __restrict__ bi, bf16* __restrict__ out,
                                            const int* __restrict__ flag, int force_f32) {
  bool pf32 = *flag > FLAG_THRESH;
  bool xf32 = force_f32 || pf32;
  int row = blockIdx.x, t = threadIdx.x;
  float v[5];
  float s = 0.f, sq = 0.f;
  #pragma unroll
  for (int i = 0; i < 5; i++) {
    v[i] = ldx(x, (size_t)row * DIM + i * 256 + t, xf32);
    s += v[i]; sq += v[i] * v[i];
  }
  #pragma unroll
  for (int o = 32; o; o >>= 1) { s += __shfl_down(s, o); sq += __shfl_down(sq, o); }
  __shared__ float rs[4], rq[4];
  if ((t & 63) == 0) { rs[t >> 6] = s; rq[t >> 6] = sq; }
  __syncthreads();
  s = rs[0] + rs[1] + rs[2] + rs[3];
  sq = rq[0] + rq[1] + rq[2] + rq[3];
  float mean = s * (1.f / DIM);
  float var = sq * (1.f / DIM) - mean * mean;
  float rstd = rsqrtf(fmaxf(var, 0.f) + 1e-6f);
  #pragma unroll
  for (int i = 0; i < 5; i++) {
    int c = i * 256 + t;
    out[(size_t)row * DIM + c] = (bf16)((v[i] - mean) * rstd * ldx(sc, c, pf32) + ldx(bi, c, pf32));
  }
}

// ---------------- BK=64 GEMM inner step: LDS [rows][64] with chunk-XOR swizzle, 2 K-slices
// read chunk: want global chunk (ks*4+quad) of row -> stored at phys chunk ^(row&7); row&7 == l15&7
template <int TN>
__device__ __forceinline__ void gemm_step64(const bf16* As, const bf16* Bs, f32x4 (&acc)[4][TN],
                                            int wm, int wn, int quad, int l15) {
  int rsw = l15 & 7;
  #pragma unroll
  for (int ks = 0; ks < 2; ks++) {
    int csw = ((ks * 4 + quad) ^ rsw) * 8;
    bf16x8 af[4], bfr[TN];
    #pragma unroll
    for (int tm = 0; tm < 4; tm++) af[tm] = *(const bf16x8*)&As[(wm + tm * 16 + l15) * 64 + csw];
    #pragma unroll
    for (int tn = 0; tn < TN; tn++) bfr[tn] = *(const bf16x8*)&Bs[(wn + tn * 16 + l15) * 64 + csw];
    #pragma unroll
    for (int tm = 0; tm < 4; tm++)
      #pragma unroll
      for (int tn = 0; tn < TN; tn++)
        acc[tm][tn] = __builtin_amdgcn_mfma_f32_16x16x32_bf16(af[tm], bfr[tn], acc[tm][tn], 0, 0, 0);
  }
}

// ---------------- GEMM  C[M,N] = A[M,K] * Bt[N,K]^T   (128 x NT tile, BK=64, 1-barrier phase)
// m248-minimum 2-phase: per phase {STAGE(other buf, next tile) BEFORE compute; compute(cur);
// vmcnt(0) AFTER compute (stage had the whole ~400cyc compute to land -> drain ~free); ONE barrier}.
// Hazards: other waves' reads of the staged-into buf finished before the PREVIOUS barrier (lgkmcnt
// precedes their MFMAs); read-after-write covered by vmcnt(0)+barrier at the prior phase end.
// Halves barrier count vs r5 (20 vs 40 per K=1280) and removes the exposed pre-compute vmcnt wait.
// LDS [rows][64]: chunk-XOR swizzle (verified, 0 conflicts): linear gl_lds dest; SOURCE chunk =
// phys ^ (row&7); READ chunk = (ks*4+quad) ^ (l15&7). (rule 21)
// MODE 0: out bf16 = acc+bias | MODE 1: out f32 = acc+bias+res(flag dtype) | MODE 2: bf16 quickgelu
template <int MODE, int NT>
__global__ __launch_bounds__(256) void gemm_bt(const bf16* __restrict__ A, const bf16* __restrict__ Bt,
                                               const void* __restrict__ bias, const void* __restrict__ res,
                                               void* __restrict__ out, int M, int N, int K,
                                               const int* __restrict__ flag) {
  bool pf32 = *flag > FLAG_THRESH;
  constexpr int TN = NT / 32;
  constexpr int NB = NT / 32;                      // B gl_lds per stage per thread
  __shared__ bf16 As0[128 * 64];
  __shared__ bf16 As1[128 * 64];
  __shared__ bf16 Bs0[NT * 64];
  __shared__ bf16 Bs1[NT * 64];
  int tid = threadIdx.x;
  int lane = tid & 63, wv = tid >> 6;
  int quad = lane >> 4, l15 = lane & 15;
  int m0 = blockIdx.y * 128, n0 = blockIdx.x * NT;
  int wm = (wv & 1) * 64, wn = (wv >> 1) * (NT / 2);
  const bf16* Ag = A + (size_t)m0 * K;
  const bf16* Bg = Bt + (size_t)n0 * K;
  int r0 = tid >> 3;                               // base row (32-row groups per instruction)
  int c0s = ((tid & 7) ^ ((tid >> 3) & 7)) * 8;    // pre-swizzled global chunk
  f32x4 acc[4][TN];
  #pragma unroll
  for (int i = 0; i < 4; i++)
    #pragma unroll
    for (int j = 0; j < TN; j++) acc[i][j] = fz4();

#define STAGE_BT(as, bs, kk) do {                                                          \
    _Pragma("unroll")                                                                      \
    for (int j = 0; j < 4; j++)                                                            \
      gl_lds16(Ag + (size_t)(r0 + j * 32) * K + (kk) + c0s, &(as)[(tid + j * 256) * 8]);   \
    _Pragma("unroll")                                                                      \
    for (int j = 0; j < NB; j++)                                                           \
      gl_lds16(Bg + (size_t)(r0 + j * 32) * K + (kk) + c0s, &(bs)[(tid + j * 256) * 8]);   \
  } while (0)

  STAGE_BT(As0, Bs0, 0);
  S_VMCNT(0);
  S_BAR();
  for (int k0 = 0; k0 < K; k0 += 128) {
    // phase A: compute buf0, prefetch buf1 (issued first, drained after compute)
    STAGE_BT(As1, Bs1, k0 + 64);
    gemm_step64<TN>(As0, Bs0, acc, wm, wn, quad, l15);
    S_VMCNT(0);
    S_BAR();
    // phase B: compute buf1, prefetch buf0 (next iter)
    if (k0 + 128 < K) STAGE_BT(As0, Bs0, k0 + 128);
    gemm_step64<TN>(As1, Bs1, acc, wm, wn, quad, l15);
    S_VMCNT(0);
    S_BAR();
  }
#undef STAGE_BT

  #pragma unroll
  for (int tm = 0; tm < 4; tm++) {
    #pragma unroll
    for (int tn = 0; tn < TN; tn++) {
      #pragma unroll
      for (int r = 0; r < 4; r++) {
        int row = m0 + wm + tm * 16 + quad * 4 + r;
        int col = n0 + wn + tn * 16 + l15;
        size_t idx = (size_t)row * N + col;
        float vv = acc[tm][tn][r] + ldx(bias, col, pf32);
        if constexpr (MODE == 0) ((bf16*)out)[idx] = (bf16)vv;
        if constexpr (MODE == 1) ((float*)out)[idx] = vv + ldx(res, idx, pf32);
        if constexpr (MODE == 2) ((bf16*)out)[idx] = (bf16)(vv / (1.f + __expf(-1.702f * vv)));
      }
    }
  }
}

// ---------------- split-K GEMM: fp32 partials, 128x64 tile, BK=64, 1-barrier phase
__global__ __launch_bounds__(256) void gemm_sk(const bf16* __restrict__ A, const bf16* __restrict__ Bt,
                                               float* __restrict__ part, int M, int N, int K, int chunk) {
  __shared__ bf16 As0[128 * 64];
  __shared__ bf16 As1[128 * 64];
  __shared__ bf16 Bs0[64 * 64];
  __shared__ bf16 Bs1[64 * 64];
  int tid = threadIdx.x;
  int lane = tid & 63, wv = tid >> 6;
  int quad = lane >> 4, l15 = lane & 15;
  int m0 = blockIdx.y * 128, n0 = blockIdx.x * 64;
  int wm = (wv & 1) * 64, wn = (wv >> 1) * 32;
  int kb = blockIdx.z * chunk;
  const bf16* Ag = A + (size_t)m0 * K;
  const bf16* Bg = Bt + (size_t)n0 * K;
  int r0 = tid >> 3;
  int c0s = ((tid & 7) ^ ((tid >> 3) & 7)) * 8;
  f32x4 acc[4][2];
  #pragma unroll
  for (int i = 0; i < 4; i++)
    #pragma unroll
    for (int j = 0; j < 2; j++) acc[i][j] = fz4();

#define STAGE_SK(as, bs, kk) do {                                                          \
    _Pragma("unroll")                                                                      \
    for (int j = 0; j < 4; j++)                                                            \
      gl_lds16(Ag + (size_t)(r0 + j * 32) * K + (kk) + c0s, &(as)[(tid + j * 256) * 8]);   \
    _Pragma("unroll")                                                                      \
    for (int j = 0; j < 2; j++)                                                            \
      gl_lds16(Bg + (size_t)(r0 + j * 32) * K + (kk) + c0s, &(bs)[(tid + j * 256) * 8]);   \
  } while (0)

  STAGE_SK(As0, Bs0, kb);
  S_VMCNT(0);
  S_BAR();
  for (int k0 = kb; k0 < kb + chunk; k0 += 128) {
    STAGE_SK(As1, Bs1, k0 + 64);
    gemm_step64<2>(As0, Bs0, acc, wm, wn, quad, l15);
    S_VMCNT(0);
    S_BAR();
    if (k0 + 128 < kb + chunk) STAGE_SK(As0, Bs0, k0 + 128);
    gemm_step64<2>(As1, Bs1, acc, wm, wn, quad, l15);
    S_VMCNT(0);
    S_BAR();
  }
#undef STAGE_SK

  float* po = part + (size_t)blockIdx.z * M * N;
  #pragma unroll
  for (int tm = 0; tm < 4; tm++) {
    #pragma unroll
    for (int tn = 0; tn < 2; tn++) {
      #pragma unroll
      for (int r = 0; r < 4; r++) {
        int row = m0 + wm + tm * 16 + quad * 4 + r;
        int col = n0 + wn + tn * 16 + l15;
        po[(size_t)row * N + col] = acc[tm][tn][r];
      }
    }
  }
}

// ---------------- split-K reduce: out = p0 + p1 + bias[col] + res (all fp32 except bias per flag)
__global__ __launch_bounds__(256) void reduce2_k(const float* __restrict__ p0, const float* __restrict__ p1,
                                                 const void* __restrict__ bias, const float* __restrict__ res,
                                                 float* __restrict__ out, int NCOL,
                                                 const int* __restrict__ flag) {
  bool pf32 = *flag > FLAG_THRESH;
  size_t i = ((size_t)blockIdx.x * 256 + threadIdx.x) * 4;
  int col = (int)(i % NCOL);
  float4 a = *(const float4*)&p0[i];
  float4 b = *(const float4*)&p1[i];
  float4 r = *(const float4*)&res[i];
  float4 o;
  o.x = a.x + b.x + r.x + ldx(bias, col + 0, pf32);
  o.y = a.y + b.y + r.y + ldx(bias, col + 1, pf32);
  o.z = a.z + b.z + r.z + ldx(bias, col + 2, pf32);
  o.w = a.w + b.w + r.w + ldx(bias, col + 3, pf32);
  *(float4*)&out[i] = o;
}

// ---------------- RoPE IN-PLACE on qkv [seq][3840]; q scaled by 1/sqrt(80); v untouched
__global__ __launch_bounds__(256) void rope_k(bf16* __restrict__ qkv, const void* __restrict__ rot,
                                              const int* __restrict__ flag) {
  bool pf32 = *flag > FLAG_THRESH;
  int idx = blockIdx.x * 256 + threadIdx.x;
  int d = idx % 40;
  int t = idx / 40;
  int head = t & 15;
  int seq = t >> 4;
  float f1 = ldx(rot, (size_t)seq * 40 + (d >> 1), pf32);
  float f2 = ldx(rot, (size_t)seq * 40 + (d >> 1) + 20, pf32);
  float c1 = cosf(f1), s1 = sinf(f1), c2 = cosf(f2), s2 = sinf(f2);
  const float scq = 0.11180339887498949f;
  size_t base = (size_t)seq * (3 * DIM) + head * HD + d;
  float x1 = (float)qkv[base], x2 = (float)qkv[base + 40];
  qkv[base] = (bf16)((x1 * c1 - x2 * s1) * scq);
  qkv[base + 40] = (bf16)((x2 * c2 + x1 * s2) * scq);
  x1 = (float)qkv[base + DIM]; x2 = (float)qkv[base + DIM + 40];
  qkv[base + DIM] = (bf16)(x1 * c1 - x2 * s1);
  qkv[base + DIM + 40] = (bf16)(x2 * c2 + x1 * s2);
}

// ---------------- MFMA flash attention: one block per (q-tile 64, head, segment)
// LDS layout (38144 B -> 4 blocks/CU):
//   Qs 64x104 bf16 (13312 B)  -- stride 104 = 13 chunks of 16B, gcd(13,8)=1 -> conflict-free b128 reads
//   Ks 64x104 bf16 (13312 B)
//   Vt 80x72  bf16 (11520 B)  -- stride 72 = 9 chunks -> conflict-free; filled r-fast (contiguous writes)
//   Ps (4 waves x 16x72) ALIASES Qs (Q fragments hoisted to registers; Qs dead after prologue)
// T5: setprio(1) around MFMA clusters (m191: +4-7% attn; 4 blocks/CU at different phases -> arbitration)
__global__ __launch_bounds__(256, 4) void attn_k(const bf16* __restrict__ qkv, const int* __restrict__ cu,
                                                 bf16* __restrict__ out) {
  __shared__ __align__(16) char smem[38144];
  bf16* Qs = (bf16*)smem;              // stride 104
  bf16* Ks = (bf16*)(smem + 13312);    // stride 104
  bf16* Vt = (bf16*)(smem + 26624);    // stride 72
  bf16* Ps = (bf16*)smem;              // per-wave 16x72 blocks, aliases Qs
  int tid = threadIdx.x, lane = tid & 63, wv = tid >> 6;
  int quad = lane >> 4, l15 = lane & 15;
  int qt = blockIdx.x, head = blockIdx.y, seg = blockIdx.z;
  int s0 = cu[seg], s1 = cu[seg + 1];
  int q0 = s0 + qt * 64;
  if (q0 >= s1) return;
  const bf16* qh = qkv + head * HD;
  const bf16* kh = qkv + DIM + head * HD;
  const bf16* vh = qkv + 2 * DIM + head * HD;
  const int RS = 3 * DIM;
  uint4 z4; z4.x = 0; z4.y = 0; z4.z = 0; z4.w = 0;
  // zero the K-dim pad cols [80,96) once (Qs+Ks); cols [96,104) never read
  for (int i = tid; i < 128; i += 256) {
    int r = i >> 1, c = i & 1;
    *(uint4*)&Qs[r * 104 + 80 + c * 8] = z4;
    *(uint4*)&Ks[r * 104 + 80 + c * 8] = z4;
  }
  for (int i = tid; i < 640; i += 256) {
    int r = i / 10, c = i % 10;
    *(bf16x8*)&Qs[r * 104 + c * 8] = *(const bf16x8*)&qh[(size_t)(q0 + r) * RS + c * 8];
  }
  __syncthreads();
  // hoist Q fragments (loop-invariant); Qs LDS is dead after this -> reused as Ps
  bf16x8 aq[3];
  #pragma unroll
  for (int ks = 0; ks < 3; ks++)
    aq[ks] = *(const bf16x8*)&Qs[(wv * 16 + l15) * 104 + ks * 32 + quad * 8];

  float m_r[4], l_r[4];
  f32x4 oacc[5];
  #pragma unroll
  for (int r = 0; r < 4; r++) { m_r[r] = -1e30f; l_r[r] = 0.f; }
  #pragma unroll
  for (int nt = 0; nt < 5; nt++) oacc[nt] = fz4();

  for (int kt = s0; kt < s1; kt += 64) {
    __syncthreads();   // prev-iter Ks/Vt reads (and prologue Q-frag reads) complete
    // K tile: c-fast (coalesced 160B row segments)
    for (int i = tid; i < 640; i += 256) {
      int r = i / 10, c = i % 10;
      *(bf16x8*)&Ks[r * 104 + c * 8] = *(const bf16x8*)&kh[(size_t)(kt + r) * RS + c * 8];
    }
    // V tile: r-fast transpose -> each scalar-write instr is 64 lanes x 2B contiguous (conflict-free)
    for (int i = tid; i < 640; i += 256) {
      int c = i >> 6, r = i & 63;
      bf16x8 vv = *(const bf16x8*)&vh[(size_t)(kt + r) * RS + c * 8];
      #pragma unroll
      for (int j = 0; j < 8; j++) Vt[(c * 8 + j) * 72 + r] = vv[j];
    }
    __syncthreads();
    f32x4 sacc[4];
    #pragma unroll
    for (int j = 0; j < 4; j++) sacc[j] = fz4();
    __builtin_amdgcn_s_setprio(1);
    #pragma unroll
    for (int ks = 0; ks < 3; ks++) {
      #pragma unroll
      for (int j = 0; j < 4; j++) {
        bf16x8 bk = *(const bf16x8*)&Ks[(j * 16 + l15) * 104 + ks * 32 + quad * 8];
        sacc[j] = __builtin_amdgcn_mfma_f32_16x16x32_bf16(aq[ks], bk, sacc[j], 0, 0, 0);
      }
    }
    __builtin_amdgcn_s_setprio(0);
    #pragma unroll
    for (int r = 0; r < 4; r++) {
      float mx = fmaxf(fmaxf(sacc[0][r], sacc[1][r]), fmaxf(sacc[2][r], sacc[3][r]));
      #pragma unroll
      for (int o = 8; o; o >>= 1) mx = fmaxf(mx, __shfl_xor(mx, o));
      float mnew = fmaxf(m_r[r], mx);
      float alpha = __expf(m_r[r] - mnew);
      float psum = 0.f;
      #pragma unroll
      for (int j = 0; j < 4; j++) {
        float p = __expf(sacc[j][r] - mnew);
        psum += p;
        Ps[wv * 1152 + (quad * 4 + r) * 72 + j * 16 + l15] = (bf16)p;
      }
      #pragma unroll
      for (int o = 8; o; o >>= 1) psum += __shfl_xor(psum, o);
      l_r[r] = l_r[r] * alpha + psum;
      m_r[r] = mnew;
      #pragma unroll
      for (int nt = 0; nt < 5; nt++) oacc[nt][r] *= alpha;
    }
    // no barrier: Ps[wv] is wave-private; Vt stable until next loop-top barrier
    __builtin_amdgcn_s_setprio(1);
    #pragma unroll
    for (int ks = 0; ks < 2; ks++) {
      bf16x8 ap = *(const bf16x8*)&Ps[wv * 1152 + l15 * 72 + ks * 32 + quad * 8];
      #pragma unroll
      for (int nt = 0; nt < 5; nt++) {
        bf16x8 bv = *(const bf16x8*)&Vt[(nt * 16 + l15) * 72 + ks * 32 + quad * 8];
        oacc[nt] = __builtin_amdgcn_mfma_f32_16x16x32_bf16(ap, bv, oacc[nt], 0, 0, 0);
      }
    }
    __builtin_amdgcn_s_setprio(0);
  }
  #pragma unroll
  for (int nt = 0; nt < 5; nt++) {
    #pragma unroll
    for (int r = 0; r < 4; r++) {
      int row = q0 + wv * 16 + quad * 4 + r;
      int d = nt * 16 + l15;
      out[(size_t)row * DIM + head * HD + d] = (bf16)(oacc[nt][r] / l_r[r]);
    }
  }
}

// ---------------- workspace layout (max 154.7 MB; ws_size proven >= 186 MB in rounds 1-3)
// PART (split-K partials, 2 x 20.97 MB = 41.94 MB) aliases QKV+AO exactly (both dead by fc2)
#define FLAG_OFF 0UL
#define QKVT_OFF 256UL
#define PROJT_OFF 9830656UL
#define FC1T_OFF 13107456UL
#define FC2T_OFF 26214656UL
#define LN_OFF 39321856UL
#define QKV_OFF 49807616UL
#define PART_OFF 49807616UL
#define AO_OFF 81264896UL
#define H1_OFF 91750656UL
#define FC1O_OFF 112722176UL

extern "C" void kernel_launch(void* const* d_in, const int* in_sizes, int n_in,
                              void* d_out, int out_size, void* d_ws, size_t ws_size,
                              hipStream_t stream) {
  const void* hidden = d_in[0];
  const void* rot    = d_in[1];
  const int*  cu     = (const int*)d_in[2];
  const void* w_qkv  = d_in[3];
  const void* b_qkv  = d_in[4];
  const void* w_proj = d_in[5];
  const void* b_proj = d_in[6];
  const void* w_fc1  = d_in[7];
  const void* b_fc1  = d_in[8];
  const void* w_fc2  = d_in[9];
  const void* b_fc2  = d_in[10];
  const void* ln1s   = d_in[11];
  const void* ln1b   = d_in[12];
  const void* ln2s   = d_in[13];
  const void* ln2b   = d_in[14];

  char* ws = (char*)d_ws;
  int* flag   = (int*)(ws + FLAG_OFF);
  bf16* qkvT  = (bf16*)(ws + QKVT_OFF);
  bf16* projT = (bf16*)(ws + PROJT_OFF);
  bf16* fc1T  = (bf16*)(ws + FC1T_OFF);
  bf16* fc2T  = (bf16*)(ws + FC2T_OFF);
  bf16* ln_bf = (bf16*)(ws + LN_OFF);
  bf16* qkv   = (bf16*)(ws + QKV_OFF);
  float* part = (float*)(ws + PART_OFF);
  bf16* ao    = (bf16*)(ws + AO_OFF);
  float* h1   = (float*)(ws + H1_OFF);
  bf16* fc1o  = (bf16*)(ws + FC1O_OFF);

  zero_flag_k<<<1, 1, 0, stream>>>(flag);
  sniff_k<<<256, 256, 0, stream>>>((const unsigned short*)hidden, SEQ * DIM, flag);

  dim3 tb(32, 8);
  transpose_k<<<dim3(120, 40), tb, 0, stream>>>(w_qkv, qkvT, 1280, 3840, flag);
  transpose_k<<<dim3(40, 40), tb, 0, stream>>>(w_proj, projT, 1280, 1280, flag);
  transpose_k<<<dim3(160, 40), tb, 0, stream>>>(w_fc1, fc1T, 1280, 5120, flag);
  transpose_k<<<dim3(40, 160), tb, 0, stream>>>(w_fc2, fc2T, 5120, 1280, flag);

  ln_k<<<SEQ, 256, 0, stream>>>(hidden, ln1s, ln1b, ln_bf, flag, 0);
  gemm_bt<0, 128><<<dim3(30, 32), 256, 0, stream>>>(ln_bf, qkvT, b_qkv, nullptr, qkv, SEQ, 3 * DIM, DIM, flag);
  rope_k<<<10240, 256, 0, stream>>>(qkv, rot, flag);
  attn_k<<<dim3(16, NH, 4), 256, 0, stream>>>(qkv, cu, ao);
  gemm_bt<1, 64><<<dim3(20, 32), 256, 0, stream>>>(ao, projT, b_proj, hidden, h1, SEQ, DIM, DIM, flag);
  ln_k<<<SEQ, 256, 0, stream>>>(h1, ln2s, ln2b, ln_bf, flag, 1);
  gemm_bt<2, 128><<<dim3(40, 32), 256, 0, stream>>>(ln_bf, fc1T, b_fc1, nullptr, fc1o, SEQ, HIDDEN, DIM, flag);
  // fc2: split-K=2 (chunk 2560), 128x64 tiles -> 1280 blocks, then reduce with bias+residual
  gemm_sk<<<dim3(20, 32, 2), 256, 0, stream>>>(fc1o, fc2T, part, SEQ, DIM, HIDDEN, HIDDEN / 2);
  reduce2_k<<<SEQ * DIM / 1024, 256, 0, stream>>>(part, part + (size_t)SEQ * DIM, b_fc2, h1,
                                                  (float*)d_out, DIM, flag);
}

// Round 7
// 604.797 us; speedup vs baseline: 1.0269x; 1.0269x over previous
//
#include <hip/hip_runtime.h>
#include <hip/hip_bf16.h>
#include <math.h>

typedef __bf16 bf16;
typedef __bf16 bf16x8 __attribute__((ext_vector_type(8)));
typedef float f32x4 __attribute__((ext_vector_type(4)));

#define DIM 1280
#define SEQ 4096
#define NH 16
#define HD 80
#define HIDDEN 5120
#define FLAG_THRESH 4096

// counted-vmcnt + raw barrier (T4): s_barrier builtin does NOT drain vmcnt (unlike __syncthreads)
#define S_VMCNT(n) asm volatile("s_waitcnt vmcnt(" #n ")" ::: "memory")
#define S_LGKM0() asm volatile("s_waitcnt lgkmcnt(0)" ::: "memory")
#define S_BAR() __builtin_amdgcn_s_barrier()
#define SCHED0() __builtin_amdgcn_sched_barrier(0)

__device__ __forceinline__ void gl_lds16(const bf16* g, bf16* l) {
  __builtin_amdgcn_global_load_lds((const __attribute__((address_space(1))) void*)g,
                                   (__attribute__((address_space(3))) void*)l, 16, 0, 0);
}

__device__ __forceinline__ f32x4 fz4() { f32x4 v; v.x = 0.f; v.y = 0.f; v.z = 0.f; v.w = 0.f; return v; }

__device__ __forceinline__ float ldx(const void* p, size_t i, bool f32) {
  if (f32) return ((const float*)p)[i];
  return (float)((const bf16*)p)[i];
}

// ---------------- flag prologue
__global__ void zero_flag_k(int* flag) { *flag = 0; }

__global__ __launch_bounds__(256) void sniff_k(const unsigned short* h, int n, int* flag) {
  int i = blockIdx.x * 256 + threadIdx.x;
  int c = 0;
  for (int idx = i; idx < n; idx += 256 * gridDim.x) {
    int e = (h[idx] >> 7) & 0xFF;
    c += (e >= 0xC8) ? 1 : 0;
  }
  #pragma unroll
  for (int o = 32; o; o >>= 1) c += __shfl_down(c, o);
  if ((threadIdx.x & 63) == 0 && c) atomicAdd(flag, c);
}

// ---------------- transpose+convert: in[R][C] -> out[C][R] bf16
__global__ __launch_bounds__(256) void transpose_k(const void* __restrict__ in, bf16* __restrict__ out,
                                                   int R, int C, const int* __restrict__ flag) {
  bool f32 = *flag > FLAG_THRESH;
  __shared__ bf16 tile[32][33];
  int c0 = blockIdx.x * 32, r0 = blockIdx.y * 32;
  int tx = threadIdx.x, ty = threadIdx.y;
  #pragma unroll
  for (int i = 0; i < 4; i++)
    tile[ty + 8 * i][tx] = (bf16)ldx(in, (size_t)(r0 + ty + 8 * i) * C + c0 + tx, f32);
  __syncthreads();
  #pragma unroll
  for (int i = 0; i < 4; i++)
    out[(size_t)(c0 + ty + 8 * i) * R + r0 + tx] = tile[tx][ty + 8 * i];
}

// ---------------- layernorm over 1280 cols, one block per row, out bf16
__global__ __launch_bounds__(256) void ln_k(const void* __restrict__ x, const void* __restrict__ sc,
                                            const void* __restrict__ bi, bf16* __restrict__ out,
                                            const int* __restrict__ flag, int force_f32) {
  bool pf32 = *flag > FLAG_THRESH;
  bool xf32 = force_f32 || pf32;
  int row = blockIdx.x, t = threadIdx.x;
  float v[5];
  float s = 0.f, sq = 0.f;
  #pragma unroll
  for (int i = 0; i < 5; i++) {
    v[i] = ldx(x, (size_t)row * DIM + i * 256 + t, xf32);
    s += v[i]; sq += v[i] * v[i];
  }
  #pragma unroll
  for (int o = 32; o; o >>= 1) { s += __shfl_down(s, o); sq += __shfl_down(sq, o); }
  __shared__ float rs[4], rq[4];
  if ((t & 63) == 0) { rs[t >> 6] = s; rq[t >> 6] = sq; }
  __syncthreads();
  s = rs[0] + rs[1] + rs[2] + rs[3];
  sq = rq[0] + rq[1] + rq[2] + rq[3];
  float mean = s * (1.f / DIM);
  float var = sq * (1.f / DIM) - mean * mean;
  float rstd = rsqrtf(fmaxf(var, 0.f) + 1e-6f);
  #pragma unroll
  for (int i = 0; i < 5; i++) {
    int c = i * 256 + t;
    out[(size_t)row * DIM + c] = (bf16)((v[i] - mean) * rstd * ldx(sc, c, pf32) + ldx(bi, c, pf32));
  }
}

// ---------------- BK=64 GEMM inner step: LDS [rows][64] with chunk-XOR swizzle, 2 K-slices
// read chunk: want global chunk (ks*4+quad) of row -> stored at phys chunk ^(row&7); row&7 == l15&7
template <int TN>
__device__ __forceinline__ void gemm_step64(const bf16* As, const bf16* Bs, f32x4 (&acc)[4][TN],
                                            int wm, int wn, int quad, int l15) {
  int rsw = l15 & 7;
  #pragma unroll
  for (int ks = 0; ks < 2; ks++) {
    int csw = ((ks * 4 + quad) ^ rsw) * 8;
    bf16x8 af[4], bfr[TN];
    #pragma unroll
    for (int tm = 0; tm < 4; tm++) af[tm] = *(const bf16x8*)&As[(wm + tm * 16 + l15) * 64 + csw];
    #pragma unroll
    for (int tn = 0; tn < TN; tn++) bfr[tn] = *(const bf16x8*)&Bs[(wn + tn * 16 + l15) * 64 + csw];
    #pragma unroll
    for (int tm = 0; tm < 4; tm++)
      #pragma unroll
      for (int tn = 0; tn < TN; tn++)
        acc[tm][tn] = __builtin_amdgcn_mfma_f32_16x16x32_bf16(af[tm], bfr[tn], acc[tm][tn], 0, 0, 0);
  }
}

// ---------------- GEMM  C[M,N] = A[M,K] * Bt[N,K]^T   (128 x NT tile, BK=64, dbuf + counted vmcnt)
// ROUND-5 STRUCTURE (best measured: fc1 105.5us, MfmaUtil 21). Round-6's 1-barrier/post-compute
// vmcnt(0) variant REGRESSED (132us): drains the just-issued prefetch whose flight < L2 latency.
// Phase: STAGE(other) -> vmcnt(counted: other buf stays in flight) -> barrier -> compute -> barrier.
// LDS [rows][64]: chunk-XOR swizzle (verified 0 conflicts): linear gl_lds dest; SOURCE chunk =
// phys ^ (row&7); READ chunk = (ks*4+quad) ^ (l15&7). (rule 21)
// MODE 0: out bf16 = acc+bias | MODE 1: out f32 = acc+bias+res(flag dtype) | MODE 2: bf16 quickgelu
template <int MODE, int NT>
__global__ __launch_bounds__(256) void gemm_bt(const bf16* __restrict__ A, const bf16* __restrict__ Bt,
                                               const void* __restrict__ bias, const void* __restrict__ res,
                                               void* __restrict__ out, int M, int N, int K,
                                               const int* __restrict__ flag) {
  bool pf32 = *flag > FLAG_THRESH;
  constexpr int TN = NT / 32;
  constexpr int NB = NT / 32;                      // B gl_lds per stage per thread
  __shared__ bf16 As0[128 * 64];
  __shared__ bf16 As1[128 * 64];
  __shared__ bf16 Bs0[NT * 64];
  __shared__ bf16 Bs1[NT * 64];
  int tid = threadIdx.x;
  int lane = tid & 63, wv = tid >> 6;
  int quad = lane >> 4, l15 = lane & 15;
  int m0 = blockIdx.y * 128, n0 = blockIdx.x * NT;
  int wm = (wv & 1) * 64, wn = (wv >> 1) * (NT / 2);
  const bf16* Ag = A + (size_t)m0 * K;
  const bf16* Bg = Bt + (size_t)n0 * K;
  int r0 = tid >> 3;                               // base row (32-row groups per instruction)
  int c0s = ((tid & 7) ^ ((tid >> 3) & 7)) * 8;    // pre-swizzled global chunk
  f32x4 acc[4][TN];
  #pragma unroll
  for (int i = 0; i < 4; i++)
    #pragma unroll
    for (int j = 0; j < TN; j++) acc[i][j] = fz4();

#define STAGE_BT(as, bs, kk) do {                                                          \
    _Pragma("unroll")                                                                      \
    for (int j = 0; j < 4; j++)                                                            \
      gl_lds16(Ag + (size_t)(r0 + j * 32) * K + (kk) + c0s, &(as)[(tid + j * 256) * 8]);   \
    _Pragma("unroll")                                                                      \
    for (int j = 0; j < NB; j++)                                                           \
      gl_lds16(Bg + (size_t)(r0 + j * 32) * K + (kk) + c0s, &(bs)[(tid + j * 256) * 8]);   \
  } while (0)

  STAGE_BT(As0, Bs0, 0);
  for (int k0 = 0; k0 < K; k0 += 128) {
    STAGE_BT(As1, Bs1, k0 + 64);
    if constexpr (NT == 128) { S_VMCNT(8); } else { S_VMCNT(6); }   // wait buf0 only
    S_BAR();
    gemm_step64<TN>(As0, Bs0, acc, wm, wn, quad, l15);
    S_BAR();
    if (k0 + 128 < K) {
      STAGE_BT(As0, Bs0, k0 + 128);
      if constexpr (NT == 128) { S_VMCNT(8); } else { S_VMCNT(6); } // wait buf1 only
    } else {
      S_VMCNT(0);
    }
    S_BAR();
    gemm_step64<TN>(As1, Bs1, acc, wm, wn, quad, l15);
    S_BAR();
  }
#undef STAGE_BT

  #pragma unroll
  for (int tm = 0; tm < 4; tm++) {
    #pragma unroll
    for (int tn = 0; tn < TN; tn++) {
      #pragma unroll
      for (int r = 0; r < 4; r++) {
        int row = m0 + wm + tm * 16 + quad * 4 + r;
        int col = n0 + wn + tn * 16 + l15;
        size_t idx = (size_t)row * N + col;
        float vv = acc[tm][tn][r] + ldx(bias, col, pf32);
        if constexpr (MODE == 0) ((bf16*)out)[idx] = (bf16)vv;
        if constexpr (MODE == 1) ((float*)out)[idx] = vv + ldx(res, idx, pf32);
        if constexpr (MODE == 2) ((bf16*)out)[idx] = (bf16)(vv / (1.f + __expf(-1.702f * vv)));
      }
    }
  }
}

// ---------------- split-K GEMM: fp32 partials, 128x64 tile, BK=64 dbuf + counted vmcnt (r5 structure)
__global__ __launch_bounds__(256) void gemm_sk(const bf16* __restrict__ A, const bf16* __restrict__ Bt,
                                               float* __restrict__ part, int M, int N, int K, int chunk) {
  __shared__ bf16 As0[128 * 64];
  __shared__ bf16 As1[128 * 64];
  __shared__ bf16 Bs0[64 * 64];
  __shared__ bf16 Bs1[64 * 64];
  int tid = threadIdx.x;
  int lane = tid & 63, wv = tid >> 6;
  int quad = lane >> 4, l15 = lane & 15;
  int m0 = blockIdx.y * 128, n0 = blockIdx.x * 64;
  int wm = (wv & 1) * 64, wn = (wv >> 1) * 32;
  int kb = blockIdx.z * chunk;
  const bf16* Ag = A + (size_t)m0 * K;
  const bf16* Bg = Bt + (size_t)n0 * K;
  int r0 = tid >> 3;
  int c0s = ((tid & 7) ^ ((tid >> 3) & 7)) * 8;
  f32x4 acc[4][2];
  #pragma unroll
  for (int i = 0; i < 4; i++)
    #pragma unroll
    for (int j = 0; j < 2; j++) acc[i][j] = fz4();

#define STAGE_SK(as, bs, kk) do {                                                          \
    _Pragma("unroll")                                                                      \
    for (int j = 0; j < 4; j++)                                                            \
      gl_lds16(Ag + (size_t)(r0 + j * 32) * K + (kk) + c0s, &(as)[(tid + j * 256) * 8]);   \
    _Pragma("unroll")                                                                      \
    for (int j = 0; j < 2; j++)                                                            \
      gl_lds16(Bg + (size_t)(r0 + j * 32) * K + (kk) + c0s, &(bs)[(tid + j * 256) * 8]);   \
  } while (0)

  STAGE_SK(As0, Bs0, kb);
  for (int k0 = kb; k0 < kb + chunk; k0 += 128) {
    STAGE_SK(As1, Bs1, k0 + 64);
    S_VMCNT(6);
    S_BAR();
    gemm_step64<2>(As0, Bs0, acc, wm, wn, quad, l15);
    S_BAR();
    if (k0 + 128 < kb + chunk) {
      STAGE_SK(As0, Bs0, k0 + 128);
      S_VMCNT(6);
    } else {
      S_VMCNT(0);
    }
    S_BAR();
    gemm_step64<2>(As1, Bs1, acc, wm, wn, quad, l15);
    S_BAR();
  }
#undef STAGE_SK

  float* po = part + (size_t)blockIdx.z * M * N;
  #pragma unroll
  for (int tm = 0; tm < 4; tm++) {
    #pragma unroll
    for (int tn = 0; tn < 2; tn++) {
      #pragma unroll
      for (int r = 0; r < 4; r++) {
        int row = m0 + wm + tm * 16 + quad * 4 + r;
        int col = n0 + wn + tn * 16 + l15;
        po[(size_t)row * N + col] = acc[tm][tn][r];
      }
    }
  }
}

// ---------------- split-K reduce: out = p0 + p1 + bias[col] + res (all fp32 except bias per flag)
__global__ __launch_bounds__(256) void reduce2_k(const float* __restrict__ p0, const float* __restrict__ p1,
                                                 const void* __restrict__ bias, const float* __restrict__ res,
                                                 float* __restrict__ out, int NCOL,
                                                 const int* __restrict__ flag) {
  bool pf32 = *flag > FLAG_THRESH;
  size_t i = ((size_t)blockIdx.x * 256 + threadIdx.x) * 4;
  int col = (int)(i % NCOL);
  float4 a = *(const float4*)&p0[i];
  float4 b = *(const float4*)&p1[i];
  float4 r = *(const float4*)&res[i];
  float4 o;
  o.x = a.x + b.x + r.x + ldx(bias, col + 0, pf32);
  o.y = a.y + b.y + r.y + ldx(bias, col + 1, pf32);
  o.z = a.z + b.z + r.z + ldx(bias, col + 2, pf32);
  o.w = a.w + b.w + r.w + ldx(bias, col + 3, pf32);
  *(float4*)&out[i] = o;
}

// ---------------- RoPE IN-PLACE on qkv [seq][3840]; q scaled by 1/sqrt(80); v untouched
__global__ __launch_bounds__(256) void rope_k(bf16* __restrict__ qkv, const void* __restrict__ rot,
                                              const int* __restrict__ flag) {
  bool pf32 = *flag > FLAG_THRESH;
  int idx = blockIdx.x * 256 + threadIdx.x;
  int d = idx % 40;
  int t = idx / 40;
  int head = t & 15;
  int seq = t >> 4;
  float f1 = ldx(rot, (size_t)seq * 40 + (d >> 1), pf32);
  float f2 = ldx(rot, (size_t)seq * 40 + (d >> 1) + 20, pf32);
  float c1 = cosf(f1), s1 = sinf(f1), c2 = cosf(f2), s2 = sinf(f2);
  const float scq = 0.11180339887498949f;
  size_t base = (size_t)seq * (3 * DIM) + head * HD + d;
  float x1 = (float)qkv[base], x2 = (float)qkv[base + 40];
  qkv[base] = (bf16)((x1 * c1 - x2 * s1) * scq);
  qkv[base + 40] = (bf16)((x2 * c2 + x1 * s2) * scq);
  x1 = (float)qkv[base + DIM]; x2 = (float)qkv[base + DIM + 40];
  qkv[base + DIM] = (bf16)(x1 * c1 - x2 * s1);
  qkv[base + DIM + 40] = (bf16)(x2 * c2 + x1 * s2);
}

// ---------------- MFMA flash attention: one block per (q-tile 64, head, segment)
// LDS layout (38144 B -> 4 blocks/CU):
//   Qs 64x104 bf16 (13312 B)  -- stride 104 = 13 chunks of 16B, gcd(13,8)=1 -> conflict-free b128 reads
//   Ks 64x104 bf16 (13312 B)
//   Vt 80x72  bf16 (11520 B)  -- stride 72 = 9 chunks -> conflict-free; filled r-fast
//   Ps (4 waves x 16x72) ALIASES Qs (Q fragments hoisted to registers; Qs dead after prologue)
// T14 async-STAGE (this round): K/V tile staged global->REGISTERS one tile ahead; loop top writes
// regs->LDS then issues NEXT tile's global loads BEFORE the compute barrier -> HBM/L2 latency hides
// under QK+softmax+PV. Raw s_barrier + explicit lgkmcnt(0) (NOT __syncthreads: its vmcnt(0) drain
// would kill the in-flight prefetch). sched_barrier(0) after barriers per rule 18.
// T5: setprio(1) around MFMA clusters (m191).
__global__ __launch_bounds__(256, 4) void attn_k(const bf16* __restrict__ qkv, const int* __restrict__ cu,
                                                 bf16* __restrict__ out) {
  __shared__ __align__(16) char smem[38144];
  bf16* Qs = (bf16*)smem;              // stride 104
  bf16* Ks = (bf16*)(smem + 13312);    // stride 104
  bf16* Vt = (bf16*)(smem + 26624);    // stride 72
  bf16* Ps = (bf16*)smem;              // per-wave 16x72 blocks, aliases Qs
  int tid = threadIdx.x, lane = tid & 63, wv = tid >> 6;
  int quad = lane >> 4, l15 = lane & 15;
  int qt = blockIdx.x, head = blockIdx.y, seg = blockIdx.z;
  int s0 = cu[seg], s1 = cu[seg + 1];
  int q0 = s0 + qt * 64;
  if (q0 >= s1) return;
  const bf16* qh = qkv + head * HD;
  const bf16* kh = qkv + DIM + head * HD;
  const bf16* vh = qkv + 2 * DIM + head * HD;
  const int RS = 3 * DIM;
  uint4 z4; z4.x = 0; z4.y = 0; z4.z = 0; z4.w = 0;
  // zero the K-dim pad cols [80,96) once (Qs+Ks); cols [96,104) never read
  for (int i = tid; i < 128; i += 256) {
    int r = i >> 1, c = i & 1;
    *(uint4*)&Qs[r * 104 + 80 + c * 8] = z4;
    *(uint4*)&Ks[r * 104 + 80 + c * 8] = z4;
  }
  for (int i = tid; i < 640; i += 256) {
    int r = i / 10, c = i % 10;
    *(bf16x8*)&Qs[r * 104 + c * 8] = *(const bf16x8*)&qh[(size_t)(q0 + r) * RS + c * 8];
  }
  __syncthreads();
  // hoist Q fragments (loop-invariant); Qs LDS is dead after this -> reused as Ps
  bf16x8 aq[3];
  #pragma unroll
  for (int ks = 0; ks < 3; ks++)
    aq[ks] = *(const bf16x8*)&Qs[(wv * 16 + l15) * 104 + ks * 32 + quad * 8];

  // per-thread staging slots: 640 bf16x8 items over 256 threads = 2 full + 1 half (tid<128)
  int ir[3], ic8[3], vr[3], vc8[3];
  #pragma unroll
  for (int u = 0; u < 3; u++) {
    int i = tid + u * 256;
    ir[u] = i / 10; ic8[u] = (i % 10) * 8;     // K rows: c-fast
    vr[u] = i & 63; vc8[u] = (i >> 6) * 8;     // V: r-fast (transpose-friendly)
  }
  bool act2 = tid < 128;

  // prefetch tile 0 into registers
  bf16x8 kreg[3], vreg[3];
  #pragma unroll
  for (int u = 0; u < 3; u++)
    if (u < 2 || act2) {
      kreg[u] = *(const bf16x8*)&kh[(size_t)(s0 + ir[u]) * RS + ic8[u]];
      vreg[u] = *(const bf16x8*)&vh[(size_t)(s0 + vr[u]) * RS + vc8[u]];
    }

  float m_r[4], l_r[4];
  f32x4 oacc[5];
  #pragma unroll
  for (int r = 0; r < 4; r++) { m_r[r] = -1e30f; l_r[r] = 0.f; }
  #pragma unroll
  for (int nt = 0; nt < 5; nt++) oacc[nt] = fz4();

  for (int kt = s0; kt < s1; kt += 64) {
    S_BAR();            // prev-tile LDS reads all consumed (results used by MFMA before arriving here)
    SCHED0();
    // write staged regs -> LDS (K rows vectorized; V transposed via conflict-free r-fast b16 writes)
    #pragma unroll
    for (int u = 0; u < 3; u++)
      if (u < 2 || act2) {
        *(bf16x8*)&Ks[ir[u] * 104 + ic8[u]] = kreg[u];
        #pragma unroll
        for (int j = 0; j < 8; j++) Vt[(vc8[u] + j) * 72 + vr[u]] = vreg[u][j];
      }
    // issue NEXT tile's global loads (latency hides under compute below)
    if (kt + 64 < s1) {
      #pragma unroll
      for (int u = 0; u < 3; u++)
        if (u < 2 || act2) {
          kreg[u] = *(const bf16x8*)&kh[(size_t)(kt + 64 + ir[u]) * RS + ic8[u]];
          vreg[u] = *(const bf16x8*)&vh[(size_t)(kt + 64 + vr[u]) * RS + vc8[u]];
        }
    }
    S_LGKM0();          // ds_writes visible to all waves (vmcnt prefetch stays outstanding)
    S_BAR();
    SCHED0();
    f32x4 sacc[4];
    #pragma unroll
    for (int j = 0; j < 4; j++) sacc[j] = fz4();
    __builtin_amdgcn_s_setprio(1);
    #pragma unroll
    for (int ks = 0; ks < 3; ks++) {
      #pragma unroll
      for (int j = 0; j < 4; j++) {
        bf16x8 bk = *(const bf16x8*)&Ks[(j * 16 + l15) * 104 + ks * 32 + quad * 8];
        sacc[j] = __builtin_amdgcn_mfma_f32_16x16x32_bf16(aq[ks], bk, sacc[j], 0, 0, 0);
      }
    }
    __builtin_amdgcn_s_setprio(0);
    #pragma unroll
    for (int r = 0; r < 4; r++) {
      float mx = fmaxf(fmaxf(sacc[0][r], sacc[1][r]), fmaxf(sacc[2][r], sacc[3][r]));
      #pragma unroll
      for (int o = 8; o; o >>= 1) mx = fmaxf(mx, __shfl_xor(mx, o));
      float mnew = fmaxf(m_r[r], mx);
      float alpha = __expf(m_r[r] - mnew);
      float psum = 0.f;
      #pragma unroll
      for (int j = 0; j < 4; j++) {
        float p = __expf(sacc[j][r] - mnew);
        psum += p;
        Ps[wv * 1152 + (quad * 4 + r) * 72 + j * 16 + l15] = (bf16)p;
      }
      #pragma unroll
      for (int o = 8; o; o >>= 1) psum += __shfl_xor(psum, o);
      l_r[r] = l_r[r] * alpha + psum;
      m_r[r] = mnew;
      #pragma unroll
      for (int nt = 0; nt < 5; nt++) oacc[nt][r] *= alpha;
    }
    // no barrier: Ps[wv] is wave-private; Vt stable until next loop-top barrier
    __builtin_amdgcn_s_setprio(1);
    #pragma unroll
    for (int ks = 0; ks < 2; ks++) {
      bf16x8 ap = *(const bf16x8*)&Ps[wv * 1152 + l15 * 72 + ks * 32 + quad * 8];
      #pragma unroll
      for (int nt = 0; nt < 5; nt++) {
        bf16x8 bv = *(const bf16x8*)&Vt[(nt * 16 + l15) * 72 + ks * 32 + quad * 8];
        oacc[nt] = __builtin_amdgcn_mfma_f32_16x16x32_bf16(ap, bv, oacc[nt], 0, 0, 0);
      }
    }
    __builtin_amdgcn_s_setprio(0);
  }
  #pragma unroll
  for (int nt = 0; nt < 5; nt++) {
    #pragma unroll
    for (int r = 0; r < 4; r++) {
      int row = q0 + wv * 16 + quad * 4 + r;
      int d = nt * 16 + l15;
      out[(size_t)row * DIM + head * HD + d] = (bf16)(oacc[nt][r] / l_r[r]);
    }
  }
}

// ---------------- workspace layout (max 154.7 MB; ws_size proven >= 186 MB in rounds 1-3)
// PART (split-K partials, 2 x 20.97 MB = 41.94 MB) aliases QKV+AO exactly (both dead by fc2)
#define FLAG_OFF 0UL
#define QKVT_OFF 256UL
#define PROJT_OFF 9830656UL
#define FC1T_OFF 13107456UL
#define FC2T_OFF 26214656UL
#define LN_OFF 39321856UL
#define QKV_OFF 49807616UL
#define PART_OFF 49807616UL
#define AO_OFF 81264896UL
#define H1_OFF 91750656UL
#define FC1O_OFF 112722176UL

extern "C" void kernel_launch(void* const* d_in, const int* in_sizes, int n_in,
                              void* d_out, int out_size, void* d_ws, size_t ws_size,
                              hipStream_t stream) {
  const void* hidden = d_in[0];
  const void* rot    = d_in[1];
  const int*  cu     = (const int*)d_in[2];
  const void* w_qkv  = d_in[3];
  const void* b_qkv  = d_in[4];
  const void* w_proj = d_in[5];
  const void* b_proj = d_in[6];
  const void* w_fc1  = d_in[7];
  const void* b_fc1  = d_in[8];
  const void* w_fc2  = d_in[9];
  const void* b_fc2  = d_in[10];
  const void* ln1s   = d_in[11];
  const void* ln1b   = d_in[12];
  const void* ln2s   = d_in[13];
  const void* ln2b   = d_in[14];

  char* ws = (char*)d_ws;
  int* flag   = (int*)(ws + FLAG_OFF);
  bf16* qkvT  = (bf16*)(ws + QKVT_OFF);
  bf16* projT = (bf16*)(ws + PROJT_OFF);
  bf16* fc1T  = (bf16*)(ws + FC1T_OFF);
  bf16* fc2T  = (bf16*)(ws + FC2T_OFF);
  bf16* ln_bf = (bf16*)(ws + LN_OFF);
  bf16* qkv   = (bf16*)(ws + QKV_OFF);
  float* part = (float*)(ws + PART_OFF);
  bf16* ao    = (bf16*)(ws + AO_OFF);
  float* h1   = (float*)(ws + H1_OFF);
  bf16* fc1o  = (bf16*)(ws + FC1O_OFF);

  zero_flag_k<<<1, 1, 0, stream>>>(flag);
  sniff_k<<<256, 256, 0, stream>>>((const unsigned short*)hidden, SEQ * DIM, flag);

  dim3 tb(32, 8);
  transpose_k<<<dim3(120, 40), tb, 0, stream>>>(w_qkv, qkvT, 1280, 3840, flag);
  transpose_k<<<dim3(40, 40), tb, 0, stream>>>(w_proj, projT, 1280, 1280, flag);
  transpose_k<<<dim3(160, 40), tb, 0, stream>>>(w_fc1, fc1T, 1280, 5120, flag);
  transpose_k<<<dim3(40, 160), tb, 0, stream>>>(w_fc2, fc2T, 5120, 1280, flag);

  ln_k<<<SEQ, 256, 0, stream>>>(hidden, ln1s, ln1b, ln_bf, flag, 0);
  gemm_bt<0, 128><<<dim3(30, 32), 256, 0, stream>>>(ln_bf, qkvT, b_qkv, nullptr, qkv, SEQ, 3 * DIM, DIM, flag);
  rope_k<<<10240, 256, 0, stream>>>(qkv, rot, flag);
  attn_k<<<dim3(16, NH, 4), 256, 0, stream>>>(qkv, cu, ao);
  gemm_bt<1, 64><<<dim3(20, 32), 256, 0, stream>>>(ao, projT, b_proj, hidden, h1, SEQ, DIM, DIM, flag);
  ln_k<<<SEQ, 256, 0, stream>>>(h1, ln2s, ln2b, ln_bf, flag, 1);
  gemm_bt<2, 128><<<dim3(40, 32), 256, 0, stream>>>(ln_bf, fc1T, b_fc1, nullptr, fc1o, SEQ, HIDDEN, DIM, flag);
  // fc2: split-K=2 (chunk 2560), 128x64 tiles -> 1280 blocks, then reduce with bias+residual
  gemm_sk<<<dim3(20, 32, 2), 256, 0, stream>>>(fc1o, fc2T, part, SEQ, DIM, HIDDEN, HIDDEN / 2);
  reduce2_k<<<SEQ * DIM / 1024, 256, 0, stream>>>(part, part + (size_t)SEQ * DIM, b_fc2, h1,
                                                  (float*)d_out, DIM, flag);
}

// Round 9
// 594.628 us; speedup vs baseline: 1.0444x; 1.0171x over previous
//
#include <hip/hip_runtime.h>
#include <hip/hip_bf16.h>
#include <math.h>

typedef __bf16 bf16;
typedef __bf16 bf16x8 __attribute__((ext_vector_type(8)));
typedef float f32x4 __attribute__((ext_vector_type(4)));

#define DIM 1280
#define SEQ 4096
#define NH 16
#define HD 80
#define HIDDEN 5120
#define FLAG_THRESH 4096

// counted-vmcnt + raw barrier (T4): s_barrier builtin does NOT drain vmcnt (unlike __syncthreads)
#define S_VMCNT(n) asm volatile("s_waitcnt vmcnt(" #n ")" ::: "memory")
#define S_LGKM0() asm volatile("s_waitcnt lgkmcnt(0)" ::: "memory")
#define S_BAR() __builtin_amdgcn_s_barrier()
#define SCHED0() __builtin_amdgcn_sched_barrier(0)

__device__ __forceinline__ void gl_lds16(const bf16* g, bf16* l) {
  __builtin_amdgcn_global_load_lds((const __attribute__((address_space(1))) void*)g,
                                   (__attribute__((address_space(3))) void*)l, 16, 0, 0);
}

__device__ __forceinline__ f32x4 fz4() { f32x4 v; v.x = 0.f; v.y = 0.f; v.z = 0.f; v.w = 0.f; return v; }

__device__ __forceinline__ float ldx(const void* p, size_t i, bool f32) {
  if (f32) return ((const float*)p)[i];
  return (float)((const bf16*)p)[i];
}

// ---------------- flag prologue
__global__ void zero_flag_k(int* flag) { *flag = 0; }

__global__ __launch_bounds__(256) void sniff_k(const unsigned short* h, int n, int* flag) {
  int i = blockIdx.x * 256 + threadIdx.x;
  int c = 0;
  for (int idx = i; idx < n; idx += 256 * gridDim.x) {
    int e = (h[idx] >> 7) & 0xFF;
    c += (e >= 0xC8) ? 1 : 0;
  }
  #pragma unroll
  for (int o = 32; o; o >>= 1) c += __shfl_down(c, o);
  if ((threadIdx.x & 63) == 0 && c) atomicAdd(flag, c);
}

// ---------------- transpose+convert: in[R][C] -> out[C][R] bf16
__global__ __launch_bounds__(256) void transpose_k(const void* __restrict__ in, bf16* __restrict__ out,
                                                   int R, int C, const int* __restrict__ flag) {
  bool f32 = *flag > FLAG_THRESH;
  __shared__ bf16 tile[32][33];
  int c0 = blockIdx.x * 32, r0 = blockIdx.y * 32;
  int tx = threadIdx.x, ty = threadIdx.y;
  #pragma unroll
  for (int i = 0; i < 4; i++)
    tile[ty + 8 * i][tx] = (bf16)ldx(in, (size_t)(r0 + ty + 8 * i) * C + c0 + tx, f32);
  __syncthreads();
  #pragma unroll
  for (int i = 0; i < 4; i++)
    out[(size_t)(c0 + ty + 8 * i) * R + r0 + tx] = tile[tx][ty + 8 * i];
}

// ---------------- layernorm over 1280 cols, one block per row, out bf16
__global__ __launch_bounds__(256) void ln_k(const void* __restrict__ x, const void* __restrict__ sc,
                                            const void* __restrict__ bi, bf16* __restrict__ out,
                                            const int* __restrict__ flag, int force_f32) {
  bool pf32 = *flag > FLAG_THRESH;
  bool xf32 = force_f32 || pf32;
  int row = blockIdx.x, t = threadIdx.x;
  float v[5];
  float s = 0.f, sq = 0.f;
  #pragma unroll
  for (int i = 0; i < 5; i++) {
    v[i] = ldx(x, (size_t)row * DIM + i * 256 + t, xf32);
    s += v[i]; sq += v[i] * v[i];
  }
  #pragma unroll
  for (int o = 32; o; o >>= 1) { s += __shfl_down(s, o); sq += __shfl_down(sq, o); }
  __shared__ float rs[4], rq[4];
  if ((t & 63) == 0) { rs[t >> 6] = s; rq[t >> 6] = sq; }
  __syncthreads();
  s = rs[0] + rs[1] + rs[2] + rs[3];
  sq = rq[0] + rq[1] + rq[2] + rq[3];
  float mean = s * (1.f / DIM);
  float var = sq * (1.f / DIM) - mean * mean;
  float rstd = rsqrtf(fmaxf(var, 0.f) + 1e-6f);
  #pragma unroll
  for (int i = 0; i < 5; i++) {
    int c = i * 256 + t;
    out[(size_t)row * DIM + c] = (bf16)((v[i] - mean) * rstd * ldx(sc, c, pf32) + ldx(bi, c, pf32));
  }
}

// ================ 256x256 8-phase fine-interleaved GEMM (m201 port, BK=32 derivation)
// 512 thr = 8 waves (2M x 4N); per-wave C = 128x64 (8mi x 4ni), acc = 128 VGPR.
// LDS: 16 half-tile slots x 8KB = 128KB. Half-tile h: K-tile T=h>>2, part=h&3
//   (0=A rows 0-127, 1=A rows 128-255, 2=B rows 0-127, 3=B rows 128-255), slot = h&15.
// 4 K-tiles resident; stage 2 K-tiles ahead (h = 4T+8..4T+11 staged during K-tile T's 2 phases).
// Slot liveness: staged slot's prior occupant (h-16) was last read 8 phases earlier -> race-free
// with per-phase barriers (max inter-wave drift 1 phase).
// Per phase: {ds_read 8 or 4 (A-half + B at even, A-half at odd) || 2x gl_lds} -> sched+bar ->
//   setprio(1) 16 MFMA setprio(0) -> bar.  vmcnt(4) ONLY at odd phases (4 loads = next-next
//   K-tile stays in flight; never drains until tail).
// Chunk-XOR swizzle (rule 21, both sides): rows are 32 bf16 = 4 chunks of 16B; phys chunk =
//   logical ^ ((row>>1)&3). Source pre-swizzled (LDS dest linear for gl_lds); read applies same.
//   ds_read_b128: 16-lane quarter covers 8 bank-slots x 2 lanes -> conflict-free.
// MODE 0: out bf16 = acc+bias | MODE 2: out bf16 = quickgelu(acc+bias)
template <int MODE>
__global__ __launch_bounds__(512, 2) void gemm256p8(const bf16* __restrict__ A, const bf16* __restrict__ Bt,
                                                    const void* __restrict__ bias, void* __restrict__ out,
                                                    int M, int N, int K, const int* __restrict__ flag) {
  bool pf32 = *flag > FLAG_THRESH;
  __shared__ bf16 lds[16][128 * 32];
  int tid = threadIdx.x;
  int lane = tid & 63, wv = tid >> 6;
  int quad = lane >> 4, l15 = lane & 15;
  int wm = wv >> 2, wn = wv & 3;                     // 2M x 4N wave grid
  int m0 = blockIdx.y * 256, n0 = blockIdx.x * 256;
  const bf16* Ag = A + (size_t)m0 * K;
  const bf16* Bg = Bt + (size_t)n0 * K;
  int r0 = tid >> 2;                                  // staging row 0..127
  int c0s = ((tid & 3) ^ ((tid >> 3) & 3)) * 8;       // pre-swizzled source chunk (elems)
  int csw = (quad ^ ((l15 >> 1) & 3)) * 8;            // read-side phys chunk (elems)
  int bloc = (wn & 1) * 64;                           // B local row base within its half

  f32x4 acc[8][4];
  #pragma unroll
  for (int i = 0; i < 8; i++)
    #pragma unroll
    for (int j = 0; j < 4; j++) acc[i][j] = fz4();

#define STG(h) do { int _t = (h) >> 2, _p = (h) & 3;                                     \
    const bf16* _g = ((_p) < 2 ? Ag : Bg) + (size_t)(((_p) & 1) * 128 + r0) * K + _t * 32 + c0s; \
    gl_lds16(_g, &lds[(h) & 15][tid * 8]); } while (0)

  int TK = K >> 5;            // K-tiles
  int HMAX = TK << 2;         // half-tiles
  // prologue: K-tiles 0,1 (h 0..7); vmcnt(4) -> K-tile 0 landed, K-tile 1 may be in flight
  #pragma unroll
  for (int h = 0; h < 8; ++h) STG(h);
  S_VMCNT(4);
  SCHED0(); S_BAR(); SCHED0();

  for (int T = 0; T < TK; ++T) {
    const bf16* sA = lds[(4 * T + wm) & 15];
    const bf16* sB = lds[(4 * T + 2 + (wn >> 1)) & 15];
    int h0 = 4 * T + 8;
    bf16x8 a[4], b[4];
    // ---- even phase: A mih0 (4 reads) + B (4 reads); stage h0, h0+1
    #pragma unroll
    for (int m = 0; m < 4; m++)
      a[m] = *(const bf16x8*)&sA[(m * 16 + l15) * 32 + csw];
    #pragma unroll
    for (int n = 0; n < 4; n++)
      b[n] = *(const bf16x8*)&sB[(bloc + n * 16 + l15) * 32 + csw];
    if (h0 < HMAX) STG(h0);
    if (h0 + 1 < HMAX) STG(h0 + 1);
    SCHED0(); S_BAR(); SCHED0();
    __builtin_amdgcn_s_setprio(1);
    #pragma unroll
    for (int m = 0; m < 4; m++)
      #pragma unroll
      for (int n = 0; n < 4; n++)
        acc[m][n] = __builtin_amdgcn_mfma_f32_16x16x32_bf16(a[m], b[n], acc[m][n], 0, 0, 0);
    __builtin_amdgcn_s_setprio(0);
    SCHED0(); S_BAR();
    // ---- odd phase: A mih1 (4 reads), reuse b; stage h0+2, h0+3; counted vmcnt
    #pragma unroll
    for (int m = 0; m < 4; m++)
      a[m] = *(const bf16x8*)&sA[((64 + m * 16 + l15)) * 32 + csw];
    if (h0 + 2 < HMAX) STG(h0 + 2);
    if (h0 + 3 < HMAX) STG(h0 + 3);
    if (h0 + 3 < HMAX) { S_VMCNT(4); } else { S_VMCNT(0); }   // tail: drain (cheap, last ~2 tiles)
    SCHED0(); S_BAR(); SCHED0();
    __builtin_amdgcn_s_setprio(1);
    #pragma unroll
    for (int m = 0; m < 4; m++)
      #pragma unroll
      for (int n = 0; n < 4; n++)
        acc[4 + m][n] = __builtin_amdgcn_mfma_f32_16x16x32_bf16(a[m], b[n], acc[4 + m][n], 0, 0, 0);
    __builtin_amdgcn_s_setprio(0);
    SCHED0(); S_BAR();
  }
#undef STG

  #pragma unroll
  for (int n = 0; n < 4; n++) {
    int col = n0 + wn * 64 + n * 16 + l15;
    float bv = ldx(bias, col, pf32);
    #pragma unroll
    for (int m = 0; m < 8; m++) {
      #pragma unroll
      for (int r = 0; r < 4; r++) {
        int row = m0 + wm * 128 + m * 16 + quad * 4 + r;
        size_t idx = (size_t)row * N + col;
        float vv = acc[m][n][r] + bv;
        if constexpr (MODE == 0) ((bf16*)out)[idx] = (bf16)vv;
        if constexpr (MODE == 2) ((bf16*)out)[idx] = (bf16)(vv / (1.f + __expf(-1.702f * vv)));
      }
    }
  }
}

// ---------------- BK=64 GEMM inner step: LDS [rows][64] with chunk-XOR swizzle, 2 K-slices
template <int TN>
__device__ __forceinline__ void gemm_step64(const bf16* As, const bf16* Bs, f32x4 (&acc)[4][TN],
                                            int wm, int wn, int quad, int l15) {
  int rsw = l15 & 7;
  #pragma unroll
  for (int ks = 0; ks < 2; ks++) {
    int csw = ((ks * 4 + quad) ^ rsw) * 8;
    bf16x8 af[4], bfr[TN];
    #pragma unroll
    for (int tm = 0; tm < 4; tm++) af[tm] = *(const bf16x8*)&As[(wm + tm * 16 + l15) * 64 + csw];
    #pragma unroll
    for (int tn = 0; tn < TN; tn++) bfr[tn] = *(const bf16x8*)&Bs[(wn + tn * 16 + l15) * 64 + csw];
    #pragma unroll
    for (int tm = 0; tm < 4; tm++)
      #pragma unroll
      for (int tn = 0; tn < TN; tn++)
        acc[tm][tn] = __builtin_amdgcn_mfma_f32_16x16x32_bf16(af[tm], bfr[tn], acc[tm][tn], 0, 0, 0);
  }
}

// ---------------- GEMM  C[M,N] = A[M,K] * Bt[N,K]^T   (128 x NT tile, BK=64, r5 counted-vmcnt dbuf)
// Used for proj (MODE 1) only; qkv/fc1 moved to gemm256p8.
template <int MODE, int NT>
__global__ __launch_bounds__(256) void gemm_bt(const bf16* __restrict__ A, const bf16* __restrict__ Bt,
                                               const void* __restrict__ bias, const void* __restrict__ res,
                                               void* __restrict__ out, int M, int N, int K,
                                               const int* __restrict__ flag) {
  bool pf32 = *flag > FLAG_THRESH;
  constexpr int TN = NT / 32;
  constexpr int NB = NT / 32;
  __shared__ bf16 As0[128 * 64];
  __shared__ bf16 As1[128 * 64];
  __shared__ bf16 Bs0[NT * 64];
  __shared__ bf16 Bs1[NT * 64];
  int tid = threadIdx.x;
  int lane = tid & 63, wv = tid >> 6;
  int quad = lane >> 4, l15 = lane & 15;
  int m0 = blockIdx.y * 128, n0 = blockIdx.x * NT;
  int wm = (wv & 1) * 64, wn = (wv >> 1) * (NT / 2);
  const bf16* Ag = A + (size_t)m0 * K;
  const bf16* Bg = Bt + (size_t)n0 * K;
  int r0 = tid >> 3;
  int c0s = ((tid & 7) ^ ((tid >> 3) & 7)) * 8;
  f32x4 acc[4][TN];
  #pragma unroll
  for (int i = 0; i < 4; i++)
    #pragma unroll
    for (int j = 0; j < TN; j++) acc[i][j] = fz4();

#define STAGE_BT(as, bs, kk) do {                                                          \
    _Pragma("unroll")                                                                      \
    for (int j = 0; j < 4; j++)                                                            \
      gl_lds16(Ag + (size_t)(r0 + j * 32) * K + (kk) + c0s, &(as)[(tid + j * 256) * 8]);   \
    _Pragma("unroll")                                                                      \
    for (int j = 0; j < NB; j++)                                                           \
      gl_lds16(Bg + (size_t)(r0 + j * 32) * K + (kk) + c0s, &(bs)[(tid + j * 256) * 8]);   \
  } while (0)

  STAGE_BT(As0, Bs0, 0);
  for (int k0 = 0; k0 < K; k0 += 128) {
    STAGE_BT(As1, Bs1, k0 + 64);
    if constexpr (NT == 128) { S_VMCNT(8); } else { S_VMCNT(6); }
    S_BAR();
    gemm_step64<TN>(As0, Bs0, acc, wm, wn, quad, l15);
    S_BAR();
    if (k0 + 128 < K) {
      STAGE_BT(As0, Bs0, k0 + 128);
      if constexpr (NT == 128) { S_VMCNT(8); } else { S_VMCNT(6); }
    } else {
      S_VMCNT(0);
    }
    S_BAR();
    gemm_step64<TN>(As1, Bs1, acc, wm, wn, quad, l15);
    S_BAR();
  }
#undef STAGE_BT

  #pragma unroll
  for (int tm = 0; tm < 4; tm++) {
    #pragma unroll
    for (int tn = 0; tn < TN; tn++) {
      #pragma unroll
      for (int r = 0; r < 4; r++) {
        int row = m0 + wm + tm * 16 + quad * 4 + r;
        int col = n0 + wn + tn * 16 + l15;
        size_t idx = (size_t)row * N + col;
        float vv = acc[tm][tn][r] + ldx(bias, col, pf32);
        if constexpr (MODE == 0) ((bf16*)out)[idx] = (bf16)vv;
        if constexpr (MODE == 1) ((float*)out)[idx] = vv + ldx(res, idx, pf32);
        if constexpr (MODE == 2) ((bf16*)out)[idx] = (bf16)(vv / (1.f + __expf(-1.702f * vv)));
      }
    }
  }
}

// ---------------- split-K GEMM: fp32 partials, 128x64 tile, BK=64 dbuf + counted vmcnt (r5)
__global__ __launch_bounds__(256) void gemm_sk(const bf16* __restrict__ A, const bf16* __restrict__ Bt,
                                               float* __restrict__ part, int M, int N, int K, int chunk) {
  __shared__ bf16 As0[128 * 64];
  __shared__ bf16 As1[128 * 64];
  __shared__ bf16 Bs0[64 * 64];
  __shared__ bf16 Bs1[64 * 64];
  int tid = threadIdx.x;
  int lane = tid & 63, wv = tid >> 6;
  int quad = lane >> 4, l15 = lane & 15;
  int m0 = blockIdx.y * 128, n0 = blockIdx.x * 64;
  int wm = (wv & 1) * 64, wn = (wv >> 1) * 32;
  int kb = blockIdx.z * chunk;
  const bf16* Ag = A + (size_t)m0 * K;
  const bf16* Bg = Bt + (size_t)n0 * K;
  int r0 = tid >> 3;
  int c0s = ((tid & 7) ^ ((tid >> 3) & 7)) * 8;
  f32x4 acc[4][2];
  #pragma unroll
  for (int i = 0; i < 4; i++)
    #pragma unroll
    for (int j = 0; j < 2; j++) acc[i][j] = fz4();

#define STAGE_SK(as, bs, kk) do {                                                          \
    _Pragma("unroll")                                                                      \
    for (int j = 0; j < 4; j++)                                                            \
      gl_lds16(Ag + (size_t)(r0 + j * 32) * K + (kk) + c0s, &(as)[(tid + j * 256) * 8]);   \
    _Pragma("unroll")                                                                      \
    for (int j = 0; j < 2; j++)                                                            \
      gl_lds16(Bg + (size_t)(r0 + j * 32) * K + (kk) + c0s, &(bs)[(tid + j * 256) * 8]);   \
  } while (0)

  STAGE_SK(As0, Bs0, kb);
  for (int k0 = kb; k0 < kb + chunk; k0 += 128) {
    STAGE_SK(As1, Bs1, k0 + 64);
    S_VMCNT(6);
    S_BAR();
    gemm_step64<2>(As0, Bs0, acc, wm, wn, quad, l15);
    S_BAR();
    if (k0 + 128 < kb + chunk) {
      STAGE_SK(As0, Bs0, k0 + 128);
      S_VMCNT(6);
    } else {
      S_VMCNT(0);
    }
    S_BAR();
    gemm_step64<2>(As1, Bs1, acc, wm, wn, quad, l15);
    S_BAR();
  }
#undef STAGE_SK

  float* po = part + (size_t)blockIdx.z * M * N;
  #pragma unroll
  for (int tm = 0; tm < 4; tm++) {
    #pragma unroll
    for (int tn = 0; tn < 2; tn++) {
      #pragma unroll
      for (int r = 0; r < 4; r++) {
        int row = m0 + wm + tm * 16 + quad * 4 + r;
        int col = n0 + wn + tn * 16 + l15;
        po[(size_t)row * N + col] = acc[tm][tn][r];
      }
    }
  }
}

// ---------------- split-K reduce: out = p0 + p1 + bias[col] + res (all fp32 except bias per flag)
__global__ __launch_bounds__(256) void reduce2_k(const float* __restrict__ p0, const float* __restrict__ p1,
                                                 const void* __restrict__ bias, const float* __restrict__ res,
                                                 float* __restrict__ out, int NCOL,
                                                 const int* __restrict__ flag) {
  bool pf32 = *flag > FLAG_THRESH;
  size_t i = ((size_t)blockIdx.x * 256 + threadIdx.x) * 4;
  int col = (int)(i % NCOL);
  float4 a = *(const float4*)&p0[i];
  float4 b = *(const float4*)&p1[i];
  float4 r = *(const float4*)&res[i];
  float4 o;
  o.x = a.x + b.x + r.x + ldx(bias, col + 0, pf32);
  o.y = a.y + b.y + r.y + ldx(bias, col + 1, pf32);
  o.z = a.z + b.z + r.z + ldx(bias, col + 2, pf32);
  o.w = a.w + b.w + r.w + ldx(bias, col + 3, pf32);
  *(float4*)&out[i] = o;
}

// ---------------- RoPE IN-PLACE on qkv [seq][3840]; q scaled by 1/sqrt(80); v untouched
__global__ __launch_bounds__(256) void rope_k(bf16* __restrict__ qkv, const void* __restrict__ rot,
                                              const int* __restrict__ flag) {
  bool pf32 = *flag > FLAG_THRESH;
  int idx = blockIdx.x * 256 + threadIdx.x;
  int d = idx % 40;
  int t = idx / 40;
  int head = t & 15;
  int seq = t >> 4;
  float f1 = ldx(rot, (size_t)seq * 40 + (d >> 1), pf32);
  float f2 = ldx(rot, (size_t)seq * 40 + (d >> 1) + 20, pf32);
  float c1 = cosf(f1), s1 = sinf(f1), c2 = cosf(f2), s2 = sinf(f2);
  const float scq = 0.11180339887498949f;
  size_t base = (size_t)seq * (3 * DIM) + head * HD + d;
  float x1 = (float)qkv[base], x2 = (float)qkv[base + 40];
  qkv[base] = (bf16)((x1 * c1 - x2 * s1) * scq);
  qkv[base + 40] = (bf16)((x2 * c2 + x1 * s2) * scq);
  x1 = (float)qkv[base + DIM]; x2 = (float)qkv[base + DIM + 40];
  qkv[base + DIM] = (bf16)(x1 * c1 - x2 * s1);
  qkv[base + DIM + 40] = (bf16)(x2 * c2 + x1 * s2);
}

// ---------------- MFMA flash attention (r7 state: async-STAGE T14, padded conflict-free strides)
__global__ __launch_bounds__(256, 4) void attn_k(const bf16* __restrict__ qkv, const int* __restrict__ cu,
                                                 bf16* __restrict__ out) {
  __shared__ __align__(16) char smem[38144];
  bf16* Qs = (bf16*)smem;              // stride 104
  bf16* Ks = (bf16*)(smem + 13312);    // stride 104
  bf16* Vt = (bf16*)(smem + 26624);    // stride 72
  bf16* Ps = (bf16*)smem;              // per-wave 16x72 blocks, aliases Qs
  int tid = threadIdx.x, lane = tid & 63, wv = tid >> 6;
  int quad = lane >> 4, l15 = lane & 15;
  int qt = blockIdx.x, head = blockIdx.y, seg = blockIdx.z;
  int s0 = cu[seg], s1 = cu[seg + 1];
  int q0 = s0 + qt * 64;
  if (q0 >= s1) return;
  const bf16* qh = qkv + head * HD;
  const bf16* kh = qkv + DIM + head * HD;
  const bf16* vh = qkv + 2 * DIM + head * HD;
  const int RS = 3 * DIM;
  uint4 z4; z4.x = 0; z4.y = 0; z4.z = 0; z4.w = 0;
  for (int i = tid; i < 128; i += 256) {
    int r = i >> 1, c = i & 1;
    *(uint4*)&Qs[r * 104 + 80 + c * 8] = z4;
    *(uint4*)&Ks[r * 104 + 80 + c * 8] = z4;
  }
  for (int i = tid; i < 640; i += 256) {
    int r = i / 10, c = i % 10;
    *(bf16x8*)&Qs[r * 104 + c * 8] = *(const bf16x8*)&qh[(size_t)(q0 + r) * RS + c * 8];
  }
  __syncthreads();
  bf16x8 aq[3];
  #pragma unroll
  for (int ks = 0; ks < 3; ks++)
    aq[ks] = *(const bf16x8*)&Qs[(wv * 16 + l15) * 104 + ks * 32 + quad * 8];

  int ir[3], ic8[3], vr[3], vc8[3];
  #pragma unroll
  for (int u = 0; u < 3; u++) {
    int i = tid + u * 256;
    ir[u] = i / 10; ic8[u] = (i % 10) * 8;
    vr[u] = i & 63; vc8[u] = (i >> 6) * 8;
  }
  bool act2 = tid < 128;

  bf16x8 kreg[3], vreg[3];
  #pragma unroll
  for (int u = 0; u < 3; u++)
    if (u < 2 || act2) {
      kreg[u] = *(const bf16x8*)&kh[(size_t)(s0 + ir[u]) * RS + ic8[u]];
      vreg[u] = *(const bf16x8*)&vh[(size_t)(s0 + vr[u]) * RS + vc8[u]];
    }

  float m_r[4], l_r[4];
  f32x4 oacc[5];
  #pragma unroll
  for (int r = 0; r < 4; r++) { m_r[r] = -1e30f; l_r[r] = 0.f; }
  #pragma unroll
  for (int nt = 0; nt < 5; nt++) oacc[nt] = fz4();

  for (int kt = s0; kt < s1; kt += 64) {
    S_BAR();
    SCHED0();
    #pragma unroll
    for (int u = 0; u < 3; u++)
      if (u < 2 || act2) {
        *(bf16x8*)&Ks[ir[u] * 104 + ic8[u]] = kreg[u];
        #pragma unroll
        for (int j = 0; j < 8; j++) Vt[(vc8[u] + j) * 72 + vr[u]] = vreg[u][j];
      }
    if (kt + 64 < s1) {
      #pragma unroll
      for (int u = 0; u < 3; u++)
        if (u < 2 || act2) {
          kreg[u] = *(const bf16x8*)&kh[(size_t)(kt + 64 + ir[u]) * RS + ic8[u]];
          vreg[u] = *(const bf16x8*)&vh[(size_t)(kt + 64 + vr[u]) * RS + vc8[u]];
        }
    }
    S_LGKM0();
    S_BAR();
    SCHED0();
    f32x4 sacc[4];
    #pragma unroll
    for (int j = 0; j < 4; j++) sacc[j] = fz4();
    __builtin_amdgcn_s_setprio(1);
    #pragma unroll
    for (int ks = 0; ks < 3; ks++) {
      #pragma unroll
      for (int j = 0; j < 4; j++) {
        bf16x8 bk = *(const bf16x8*)&Ks[(j * 16 + l15) * 104 + ks * 32 + quad * 8];
        sacc[j] = __builtin_amdgcn_mfma_f32_16x16x32_bf16(aq[ks], bk, sacc[j], 0, 0, 0);
      }
    }
    __builtin_amdgcn_s_setprio(0);
    #pragma unroll
    for (int r = 0; r < 4; r++) {
      float mx = fmaxf(fmaxf(sacc[0][r], sacc[1][r]), fmaxf(sacc[2][r], sacc[3][r]));
      #pragma unroll
      for (int o = 8; o; o >>= 1) mx = fmaxf(mx, __shfl_xor(mx, o));
      float mnew = fmaxf(m_r[r], mx);
      float alpha = __expf(m_r[r] - mnew);
      float psum = 0.f;
      #pragma unroll
      for (int j = 0; j < 4; j++) {
        float p = __expf(sacc[j][r] - mnew);
        psum += p;
        Ps[wv * 1152 + (quad * 4 + r) * 72 + j * 16 + l15] = (bf16)p;
      }
      #pragma unroll
      for (int o = 8; o; o >>= 1) psum += __shfl_xor(psum, o);
      l_r[r] = l_r[r] * alpha + psum;
      m_r[r] = mnew;
      #pragma unroll
      for (int nt = 0; nt < 5; nt++) oacc[nt][r] *= alpha;
    }
    __builtin_amdgcn_s_setprio(1);
    #pragma unroll
    for (int ks = 0; ks < 2; ks++) {
      bf16x8 ap = *(const bf16x8*)&Ps[wv * 1152 + l15 * 72 + ks * 32 + quad * 8];
      #pragma unroll
      for (int nt = 0; nt < 5; nt++) {
        bf16x8 bv = *(const bf16x8*)&Vt[(nt * 16 + l15) * 72 + ks * 32 + quad * 8];
        oacc[nt] = __builtin_amdgcn_mfma_f32_16x16x32_bf16(ap, bv, oacc[nt], 0, 0, 0);
      }
    }
    __builtin_amdgcn_s_setprio(0);
  }
  #pragma unroll
  for (int nt = 0; nt < 5; nt++) {
    #pragma unroll
    for (int r = 0; r < 4; r++) {
      int row = q0 + wv * 16 + quad * 4 + r;
      int d = nt * 16 + l15;
      out[(size_t)row * DIM + head * HD + d] = (bf16)(oacc[nt][r] / l_r[r]);
    }
  }
}

// ---------------- workspace layout (max 154.7 MB; ws_size proven >= 186 MB in rounds 1-3)
// PART (split-K partials, 2 x 20.97 MB = 41.94 MB) aliases QKV+AO exactly (both dead by fc2)
#define FLAG_OFF 0UL
#define QKVT_OFF 256UL
#define PROJT_OFF 9830656UL
#define FC1T_OFF 13107456UL
#define FC2T_OFF 26214656UL
#define LN_OFF 39321856UL
#define QKV_OFF 49807616UL
#define PART_OFF 49807616UL
#define AO_OFF 81264896UL
#define H1_OFF 91750656UL
#define FC1O_OFF 112722176UL

extern "C" void kernel_launch(void* const* d_in, const int* in_sizes, int n_in,
                              void* d_out, int out_size, void* d_ws, size_t ws_size,
                              hipStream_t stream) {
  const void* hidden = d_in[0];
  const void* rot    = d_in[1];
  const int*  cu     = (const int*)d_in[2];
  const void* w_qkv  = d_in[3];
  const void* b_qkv  = d_in[4];
  const void* w_proj = d_in[5];
  const void* b_proj = d_in[6];
  const void* w_fc1  = d_in[7];
  const void* b_fc1  = d_in[8];
  const void* w_fc2  = d_in[9];
  const void* b_fc2  = d_in[10];
  const void* ln1s   = d_in[11];
  const void* ln1b   = d_in[12];
  const void* ln2s   = d_in[13];
  const void* ln2b   = d_in[14];

  char* ws = (char*)d_ws;
  int* flag   = (int*)(ws + FLAG_OFF);
  bf16* qkvT  = (bf16*)(ws + QKVT_OFF);
  bf16* projT = (bf16*)(ws + PROJT_OFF);
  bf16* fc1T  = (bf16*)(ws + FC1T_OFF);
  bf16* fc2T  = (bf16*)(ws + FC2T_OFF);
  bf16* ln_bf = (bf16*)(ws + LN_OFF);
  bf16* qkv   = (bf16*)(ws + QKV_OFF);
  float* part = (float*)(ws + PART_OFF);
  bf16* ao    = (bf16*)(ws + AO_OFF);
  float* h1   = (float*)(ws + H1_OFF);
  bf16* fc1o  = (bf16*)(ws + FC1O_OFF);

  zero_flag_k<<<1, 1, 0, stream>>>(flag);
  sniff_k<<<256, 256, 0, stream>>>((const unsigned short*)hidden, SEQ * DIM, flag);

  dim3 tb(32, 8);
  transpose_k<<<dim3(120, 40), tb, 0, stream>>>(w_qkv, qkvT, 1280, 3840, flag);
  transpose_k<<<dim3(40, 40), tb, 0, stream>>>(w_proj, projT, 1280, 1280, flag);
  transpose_k<<<dim3(160, 40), tb, 0, stream>>>(w_fc1, fc1T, 1280, 5120, flag);
  transpose_k<<<dim3(40, 160), tb, 0, stream>>>(w_fc2, fc2T, 5120, 1280, flag);

  ln_k<<<SEQ, 256, 0, stream>>>(hidden, ln1s, ln1b, ln_bf, flag, 0);
  gemm256p8<0><<<dim3(15, 16), 512, 0, stream>>>(ln_bf, qkvT, b_qkv, qkv, SEQ, 3 * DIM, DIM, flag);
  rope_k<<<10240, 256, 0, stream>>>(qkv, rot, flag);
  attn_k<<<dim3(16, NH, 4), 256, 0, stream>>>(qkv, cu, ao);
  gemm_bt<1, 64><<<dim3(20, 32), 256, 0, stream>>>(ao, projT, b_proj, hidden, h1, SEQ, DIM, DIM, flag);
  ln_k<<<SEQ, 256, 0, stream>>>(h1, ln2s, ln2b, ln_bf, flag, 1);
  gemm256p8<2><<<dim3(20, 16), 512, 0, stream>>>(ln_bf, fc1T, b_fc1, fc1o, SEQ, HIDDEN, DIM, flag);
  // fc2: split-K=2 (chunk 2560), 128x64 tiles -> 1280 blocks, then reduce with bias+residual
  gemm_sk<<<dim3(20, 32, 2), 256, 0, stream>>>(fc1o, fc2T, part, SEQ, DIM, HIDDEN, HIDDEN / 2);
  reduce2_k<<<SEQ * DIM / 1024, 256, 0, stream>>>(part, part + (size_t)SEQ * DIM, b_fc2, h1,
                                                  (float*)d_out, DIM, flag);
}